// Round 6
// baseline (522.025 us; speedup 1.0000x reference)
//
#include <hip/hip_runtime.h>
#include <math.h>
#include <stdint.h>

#define BATCH 4
#define C_DIM 256
#define HW    4096
#define KT    32
#define NSPLIT 4
#define KRANGE (HW / NSPLIT)      // 1024
#define NT_WG (KRANGE / KT)       // 32
#define LOG2E 1.44269504088896340736f

typedef _Float16 half8 __attribute__((ext_vector_type(8)));
typedef float f32x4 __attribute__((ext_vector_type(4)));
typedef int i32x4 __attribute__((ext_vector_type(4)));
typedef unsigned int u32;

#define MFMA16(a, b, c) __builtin_amdgcn_mfma_f32_16x16x32_f16(a, b, c, 0, 0, 0)

#define GLL16(gsrc, ldst) \
  __builtin_amdgcn_global_load_lds((const __attribute__((address_space(1))) u32*)(const void*)(gsrc), \
                                   (__attribute__((address_space(3))) u32*)(void*)(ldst), 16, 0, 0)

// ---------------------------------------------------------------------------
// cvt: x f32 [b][c][p] -> xT hi/lo fp16 [b][p][c]   (transpose + split)
// ---------------------------------------------------------------------------
__global__ __launch_bounds__(256) void cvt_tsplit(
    const float* __restrict__ x, _Float16* __restrict__ xh, _Float16* __restrict__ xl)
{
    __shared__ float Xs[64][65];
    const int b = blockIdx.z, c0 = blockIdx.y * 64, p0 = blockIdx.x * 64;
    const int tid = threadIdx.x;
    #pragma unroll
    for (int it = 0; it < 16; ++it) {
        int idx = tid + it * 256;
        int row = idx >> 6, col = idx & 63;
        Xs[row][col] = x[((size_t)b * C_DIM + c0 + row) * HW + p0 + col];
    }
    __syncthreads();
    #pragma unroll
    for (int it = 0; it < 16; ++it) {
        int idx = tid + it * 256;
        int p_l = idx >> 6, c_l = idx & 63;
        float v = Xs[c_l][p_l];
        _Float16 h = (_Float16)v;
        size_t g = ((size_t)b * HW + p0 + p_l) * C_DIM + c0 + c_l;
        xh[g] = h;
        xl[g] = (_Float16)(v - (float)h);
    }
}

// ---------------------------------------------------------------------------
// wsplit: 4 weight matrices f32 [256][256] -> Wh/Wl fp16 (natural layout)
// ---------------------------------------------------------------------------
__global__ __launch_bounds__(256) void wsplit(
    const float* __restrict__ w1, const float* __restrict__ w2,
    const float* __restrict__ w3, const float* __restrict__ w4,
    _Float16* __restrict__ Wh, _Float16* __restrict__ Wl)
{
    const int m = blockIdx.y;
    const float* src = (m == 0) ? w1 : (m == 1) ? w2 : (m == 2) ? w3 : w4;
    const int i = blockIdx.x * 256 + threadIdx.x;
    float v = src[i];
    _Float16 h = (_Float16)v;
    Wh[m * 65536 + i] = h;
    Wl[m * 65536 + i] = (_Float16)(v - (float)h);
}

// ---------------------------------------------------------------------------
// conv1x1 as split-fp16 MFMA GEMM (unchanged from R4 — proven).
// ---------------------------------------------------------------------------
template<int MODE>
__global__ __launch_bounds__(256, 3) void conv_mfma(
    const _Float16* __restrict__ Wh, const _Float16* __restrict__ Wl,
    const _Float16* __restrict__ Xh, const _Float16* __restrict__ Xl,
    const float* __restrict__ bias,
    const float* __restrict__ res, float* __restrict__ outf,
    _Float16* __restrict__ oh, _Float16* __restrict__ ol)
{
    __shared__ __align__(1024) char smem[49152];
    char* const AH = smem;
    char* const AL = smem + 8192;
    char* const BH = smem + 16384;
    char* const BL = smem + 32768;

    const int tid = threadIdx.x;
    const int lane = tid & 63;
    const int w = tid >> 6;
    const int l15 = lane & 15, l4 = lane >> 4;
    const int o0 = blockIdx.y * 64;
    const int gp0 = blockIdx.x * 128;

    auto stage = [&](int ks) {
        const int kc0 = ks * 64;
        #pragma unroll
        for (int i = 0; i < 2; ++i) {
            const int r0 = w * 16 + i * 8;
            const int row = r0 + (lane >> 3);
            const int cc = ((lane & 7) ^ (row & 7)) * 8 + kc0;
            const size_t g = (size_t)(o0 + row) * C_DIM + cc;
            GLL16(Wh + g, AH + r0 * 128);
            GLL16(Wl + g, AL + r0 * 128);
        }
        #pragma unroll
        for (int i = 0; i < 4; ++i) {
            const int r0 = w * 32 + i * 8;
            const int p = r0 + (lane >> 3);
            const int cc = ((lane & 7) ^ (p & 7)) * 8 + kc0;
            const size_t g = (size_t)(gp0 + p) * C_DIM + cc;
            GLL16(Xh + g, BH + r0 * 128);
            GLL16(Xl + g, BL + r0 * 128);
        }
    };

    f32x4 acc[4][4];
    #pragma unroll
    for (int i = 0; i < 4; ++i)
        #pragma unroll
        for (int j = 0; j < 4; ++j) {
            f32x4 z = {0.f, 0.f, 0.f, 0.f};
            acc[i][j] = z;
        }

    stage(0);
    for (int ks = 0; ks < 4; ++ks) {
        __syncthreads();
        #pragma unroll
        for (int s = 0; s < 2; ++s) {
            const int coff = s * 64 + l4 * 16;
            if (MODE == 0) {
                half8 ah[4], al[4], bh[2], bl[2];
                #pragma unroll
                for (int mt = 0; mt < 4; ++mt) {
                    const int ol_ = mt * 16 + l15;
                    const int sw = (ol_ & 7) << 4;
                    ah[mt] = *(const half8*)(AH + ol_ * 128 + (coff ^ sw));
                    al[mt] = *(const half8*)(AL + ol_ * 128 + (coff ^ sw));
                }
                #pragma unroll
                for (int nt = 0; nt < 2; ++nt) {
                    const int pl_ = w * 32 + nt * 16 + l15;
                    const int sw = (pl_ & 7) << 4;
                    bh[nt] = *(const half8*)(BH + pl_ * 128 + (coff ^ sw));
                    bl[nt] = *(const half8*)(BL + pl_ * 128 + (coff ^ sw));
                }
                #pragma unroll
                for (int mt = 0; mt < 4; ++mt)
                    #pragma unroll
                    for (int nt = 0; nt < 2; ++nt) {
                        acc[mt][nt] = MFMA16(ah[mt], bh[nt], acc[mt][nt]);
                        acc[mt][nt] = MFMA16(al[mt], bh[nt], acc[mt][nt]);
                        acc[mt][nt] = MFMA16(ah[mt], bl[nt], acc[mt][nt]);
                    }
            } else {
                half8 ah[2], al[2], bh[4], bl[4];
                #pragma unroll
                for (int mt = 0; mt < 2; ++mt) {
                    const int pl_ = w * 32 + mt * 16 + l15;
                    const int sw = (pl_ & 7) << 4;
                    ah[mt] = *(const half8*)(BH + pl_ * 128 + (coff ^ sw));
                    al[mt] = *(const half8*)(BL + pl_ * 128 + (coff ^ sw));
                }
                #pragma unroll
                for (int nt = 0; nt < 4; ++nt) {
                    const int ol_ = nt * 16 + l15;
                    const int sw = (ol_ & 7) << 4;
                    bh[nt] = *(const half8*)(AH + ol_ * 128 + (coff ^ sw));
                    bl[nt] = *(const half8*)(AL + ol_ * 128 + (coff ^ sw));
                }
                #pragma unroll
                for (int mt = 0; mt < 2; ++mt)
                    #pragma unroll
                    for (int nt = 0; nt < 4; ++nt) {
                        acc[mt][nt] = MFMA16(ah[mt], bh[nt], acc[mt][nt]);
                        acc[mt][nt] = MFMA16(al[mt], bh[nt], acc[mt][nt]);
                        acc[mt][nt] = MFMA16(ah[mt], bl[nt], acc[mt][nt]);
                    }
            }
        }
        __syncthreads();
        if (ks < 3) stage(ks + 1);
    }

    if (MODE == 0) {
        float bv[4][4];
        #pragma unroll
        for (int mt = 0; mt < 4; ++mt)
            #pragma unroll
            for (int r = 0; r < 4; ++r)
                bv[mt][r] = bias[o0 + mt * 16 + l4 * 4 + r];
        #pragma unroll
        for (int nt = 0; nt < 2; ++nt) {
            const size_t p = gp0 + w * 32 + nt * 16 + l15;
            #pragma unroll
            for (int mt = 0; mt < 4; ++mt) {
                _Float16 hb[4], lb[4];
                #pragma unroll
                for (int r = 0; r < 4; ++r) {
                    float v = acc[mt][nt][r] + bv[mt][r];
                    _Float16 h = (_Float16)v;
                    hb[r] = h;
                    lb[r] = (_Float16)(v - (float)h);
                }
                const size_t g = p * C_DIM + o0 + mt * 16 + l4 * 4;
                *(uint2*)(oh + g) = *(uint2*)hb;
                *(uint2*)(ol + g) = *(uint2*)lb;
            }
        }
    } else {
        float bv[4];
        #pragma unroll
        for (int nt = 0; nt < 4; ++nt) bv[nt] = bias[o0 + nt * 16 + l15];
        const int b = gp0 >> 12;
        #pragma unroll
        for (int mt = 0; mt < 2; ++mt) {
            const int sp = (gp0 & 4095) + w * 32 + mt * 16 + l4 * 4;
            #pragma unroll
            for (int nt = 0; nt < 4; ++nt) {
                const int o = o0 + nt * 16 + l15;
                const size_t base = ((size_t)b * C_DIM + o) * HW + sp;
                if (MODE == 1) {
                    _Float16 hb[4];
                    #pragma unroll
                    for (int r = 0; r < 4; ++r)
                        hb[r] = (_Float16)(acc[mt][nt][r] + bv[nt]);
                    *(uint2*)(oh + base) = *(uint2*)hb;
                } else {
                    f32x4 rv = *(const f32x4*)(res + base);
                    f32x4 vv;
                    #pragma unroll
                    for (int r = 0; r < 4; ++r) vv[r] = acc[mt][nt][r] + bv[nt] + rv[r];
                    *(f32x4*)(outf + base) = vv;
                }
            }
        }
    }
}

// ---------------------------------------------------------------------------
// MFMA flash attention v3: swapped QK^T (S^T = K·Q), in-register softmax,
// P passed to PV via cvt_pkrtz + shfl (no LDS). K single-buffered LDS,
// V single-buffered LDS (fixed swizzle). LDS 48KB -> 3 blocks/CU.
// k-split x4; writes fp16 normalized partial O + (m,l).
// Per-lane ownership: q-column = l15 (wave w owns q0+w*16 .. +16).
// ---------------------------------------------------------------------------
__global__ __launch_bounds__(256, 3) void attn_mfma(
    const _Float16* __restrict__ qTh, const _Float16* __restrict__ qTl,
    const _Float16* __restrict__ kTh, const _Float16* __restrict__ kTl,
    const _Float16* __restrict__ vh,
    _Float16* __restrict__ Op01, _Float16* __restrict__ Op23,
    float2* __restrict__ ml)
{
    __shared__ __align__(1024) char smem[49152];
    char* const KH = smem;              // [32 ki][256 c] fp16, 512B rows, swz
    char* const KL = smem + 16384;
    char* const VB = smem + 32768;      // [256 c][32 k] fp16, 64B rows, swz

    const int raw = blockIdx.x;         // 1024 WGs; combo%8 = XCD
    const int combo = raw & 15;
    const int b  = combo >> 2;
    const int ks = combo & 3;
    const int q0 = (raw >> 4) * 64;
    const int kbase = ks * KRANGE;

    const int tid = threadIdx.x;
    const int lane = tid & 63;
    const int w = tid >> 6;
    const int l15 = lane & 15, l4 = lane >> 4;
    const size_t cb = (size_t)b * C_DIM * HW;

    // Q fragments (B-frag: col=q=l15, c-chunk=(lane>>4)*8+i per 32-c step)
    half8 qh[8], ql[8];
    {
        const size_t base = ((size_t)b * HW + (q0 + w * 16 + l15)) * C_DIM + l4 * 8;
        #pragma unroll
        for (int s = 0; s < 8; ++s) {
            qh[s] = *(const half8*)(qTh + base + s * 32);
            ql[s] = *(const half8*)(qTl + base + s * 32);
        }
    }

    auto stageK = [&](int t) {
        const int k0 = kbase + t * KT;
        #pragma unroll
        for (int i = 0; i < 4; ++i) {
            const int r0 = w * 8 + i * 2;
            const int row = r0 + (lane >> 5);
            const int cc = ((lane & 31) ^ (row & 7)) * 8;
            const size_t gs = ((size_t)b * HW + k0 + row) * C_DIM + cc;
            GLL16(kTh + gs, KH + r0 * 512);
            GLL16(kTl + gs, KL + r0 * 512);
        }
    };
    // V [c][k] 64B rows; swizzle key (c>>1)&3 -> read bank-quads cover all 8
    auto stageV = [&](int t) {
        const int k0 = kbase + t * KT;
        #pragma unroll
        for (int i = 0; i < 4; ++i) {
            const int c0w = w * 64 + i * 16;
            const int c = c0w + (lane >> 2);
            const int kk = ((lane & 3) ^ ((c >> 1) & 3)) * 8;
            const size_t gs = (cb + (size_t)c * HW) + k0 + kk;
            GLL16(vh + gs, VB + c0w * 64);
        }
    };

    stageK(0);
    stageV(0);

    f32x4 accv[16];                     // O[c = mt*16 + l4*4 + r][q = l15]
    #pragma unroll
    for (int mt = 0; mt < 16; ++mt) {
        f32x4 z = {0.f, 0.f, 0.f, 0.f};
        accv[mt] = z;
    }
    float m_run = -INFINITY, l_run = 0.f;

    for (int t = 0; t < NT_WG; ++t) {
        __syncthreads();   // B1: K(t)/V(t) staged (drains vmcnt)

        // ---- QK^T swapped: sacc[nt] = S^T[k = nt*16 + l4*4 + r][q = l15]
        f32x4 sacc[2];
        #pragma unroll
        for (int nt = 0; nt < 2; ++nt) {
            f32x4 z = {0.f, 0.f, 0.f, 0.f};
            sacc[nt] = z;
        }
        #pragma unroll
        for (int s = 0; s < 8; ++s) {
            const int coff = s * 64 + l4 * 16;
            #pragma unroll
            for (int nt = 0; nt < 2; ++nt) {
                const int ki = nt * 16 + l15;      // A-frag row = k
                const int sw = (ki & 7) << 4;
                half8 kf = *(const half8*)(KH + ki * 512 + (coff ^ sw));
                half8 lf = *(const half8*)(KL + ki * 512 + (coff ^ sw));
                sacc[nt] = MFMA16(kf, qh[s], sacc[nt]);
                sacc[nt] = MFMA16(kf, ql[s], sacc[nt]);
                sacc[nt] = MFMA16(lf, qh[s], sacc[nt]);
            }
        }
        __syncthreads();   // B2: all K reads done
        if (t + 1 < NT_WG) stageK(t + 1);

        // ---- in-register online softmax for q-column l15
        float mx = fmaxf(fmaxf(fmaxf(sacc[0][0], sacc[0][1]), fmaxf(sacc[0][2], sacc[0][3])),
                         fmaxf(fmaxf(sacc[1][0], sacc[1][1]), fmaxf(sacc[1][2], sacc[1][3])));
        mx = fmaxf(mx, __shfl_xor(mx, 16));
        mx = fmaxf(mx, __shfl_xor(mx, 32));
        const float mnew = fmaxf(m_run, mx);
        const float sc = exp2f((m_run - mnew) * LOG2E);
        float p[2][4];
        float rs = 0.f;
        #pragma unroll
        for (int nt = 0; nt < 2; ++nt)
            #pragma unroll
            for (int r = 0; r < 4; ++r) {
                p[nt][r] = exp2f((sacc[nt][r] - mnew) * LOG2E);
                rs += p[nt][r];
            }
        rs += __shfl_xor(rs, 16);
        rs += __shfl_xor(rs, 32);
        l_run = l_run * sc + rs;
        m_run = mnew;

        // ---- build PV B-frag: element i of half8 = P[k=l4*8+i][q=l15]
        int d0a = __builtin_bit_cast(int, __builtin_amdgcn_cvt_pkrtz(p[0][0], p[0][1]));
        int d0b = __builtin_bit_cast(int, __builtin_amdgcn_cvt_pkrtz(p[0][2], p[0][3]));
        int d1a = __builtin_bit_cast(int, __builtin_amdgcn_cvt_pkrtz(p[1][0], p[1][1]));
        int d1b = __builtin_bit_cast(int, __builtin_amdgcn_cvt_pkrtz(p[1][2], p[1][3]));
        const int src0 = l15 + (((l4 & 1) << 1) << 4);   // lane l15+16*(2*(l4&1))
        const int src1 = src0 + 16;
        const int a0 = __shfl(d0a, src0), a1 = __shfl(d0b, src0);
        const int a2 = __shfl(d0a, src1), a3 = __shfl(d0b, src1);
        const int b0 = __shfl(d1a, src0), b1 = __shfl(d1b, src0);
        const int b2 = __shfl(d1a, src1), b3 = __shfl(d1b, src1);
        const bool hi = (l4 >= 2);       // target k>=16 -> source nt=1
        i32x4 pw;
        pw[0] = hi ? b0 : a0;
        pw[1] = hi ? b1 : a1;
        pw[2] = hi ? b2 : a2;
        pw[3] = hi ? b3 : a3;
        const half8 pfrag = __builtin_bit_cast(half8, pw);

        // ---- rescale O, then O += V·P
        #pragma unroll
        for (int mt = 0; mt < 16; ++mt) {
            accv[mt][0] *= sc; accv[mt][1] *= sc;
            accv[mt][2] *= sc; accv[mt][3] *= sc;
        }
        #pragma unroll
        for (int mt = 0; mt < 16; ++mt) {
            const int c = mt * 16 + l15;     // A-frag row = c
            const half8 vf = *(const half8*)(VB + c * 64 + ((l4 ^ ((c >> 1) & 3)) << 4));
            accv[mt] = MFMA16(vf, pfrag, accv[mt]);
        }
        __syncthreads();   // B3: all V reads done
        if (t + 1 < NT_WG) stageV(t + 1);
    }

    // ---- epilogue: normalized fp16 partial + (m,l)
    const float inv = 1.0f / l_run;
    const size_t NEp = (size_t)BATCH * HW * C_DIM;
    _Float16* Op = ((ks & 2) ? Op23 : Op01) + (size_t)(ks & 1) * NEp;
    const int q = q0 + w * 16 + l15;
    const size_t gq = ((size_t)b * HW + q) * C_DIM;
    #pragma unroll
    for (int mt = 0; mt < 16; ++mt) {
        _Float16 hb[4];
        #pragma unroll
        for (int r = 0; r < 4; ++r) hb[r] = (_Float16)(accv[mt][r] * inv);
        *(uint2*)(Op + gq + mt * 16 + l4 * 4) = *(uint2*)hb;
    }
    if (l4 == 0) ml[((size_t)ks * BATCH + b) * HW + q] = make_float2(m_run, l_run);
}

// ---------------------------------------------------------------------------
// merge4: combine 4 k-split partials -> frsT hi/lo fp16 [b][q][c]
// ---------------------------------------------------------------------------
__global__ __launch_bounds__(256) void merge4(
    const _Float16* __restrict__ Op01, const _Float16* __restrict__ Op23,
    const float2* __restrict__ ml,
    _Float16* __restrict__ fh, _Float16* __restrict__ fl)
{
    const int gi = blockIdx.x * 256 + threadIdx.x;   // 0..524287
    const int c8 = gi & 31;
    const int q  = (gi >> 5) & 4095;
    const int b  = gi >> 17;
    const size_t NEp = (size_t)BATCH * HW * C_DIM;
    const size_t iq = (size_t)b * HW + q;

    float2 e[4];
    #pragma unroll
    for (int k = 0; k < 4; ++k) e[k] = ml[(size_t)k * (BATCH * HW) + iq];
    float M = fmaxf(fmaxf(e[0].x, e[1].x), fmaxf(e[2].x, e[3].x));
    float wk[4], wsum = 0.f;
    #pragma unroll
    for (int k = 0; k < 4; ++k) {
        wk[k] = e[k].y * exp2f((e[k].x - M) * LOG2E);
        wsum += wk[k];
    }
    const float r = 1.0f / wsum;
    #pragma unroll
    for (int k = 0; k < 4; ++k) wk[k] *= r;

    const size_t gb = iq * C_DIM + c8 * 8;
    half8 p0 = *(const half8*)(Op01 + gb);
    half8 p1 = *(const half8*)(Op01 + NEp + gb);
    half8 p2 = *(const half8*)(Op23 + gb);
    half8 p3 = *(const half8*)(Op23 + NEp + gb);
    _Float16 hb[8], lb[8];
    #pragma unroll
    for (int i = 0; i < 8; ++i) {
        float v = wk[0] * (float)p0[i] + wk[1] * (float)p1[i]
                + wk[2] * (float)p2[i] + wk[3] * (float)p3[i];
        _Float16 h = (_Float16)v;
        hb[i] = h;
        lb[i] = (_Float16)(v - (float)h);
    }
    *(half8*)(fh + gb) = *(half8*)hb;
    *(half8*)(fl + gb) = *(half8*)lb;
}

// ---------------------------------------------------------------------------
// Workspace (8 slots x 8 MiB = 64 MiB, R1-proven size). Overlays:
//   s0,s1: fccT -> kT -> frsT | s2,s3: fssT -> Op(ks0,ks1) | s4,s5: qT
//   s6: vhb | s7: ml(512K)+Wh(512K)+Wl(512K)
//   Op(ks2,ks3) -> d_out scratch (fully rewritten by final conv).
// ---------------------------------------------------------------------------
extern "C" void kernel_launch(void* const* d_in, const int* in_sizes, int n_in,
                              void* d_out, int out_size, void* d_ws, size_t ws_size,
                              hipStream_t stream)
{
    const float* x_fcc = (const float*)d_in[0];
    const float* x_fss = (const float*)d_in[1];
    const float* w1  = (const float*)d_in[2];
    const float* b1  = (const float*)d_in[3];
    const float* w2  = (const float*)d_in[4];
    const float* b2  = (const float*)d_in[5];
    const float* w3  = (const float*)d_in[6];
    const float* b3  = (const float*)d_in[7];
    const float* wrs = (const float*)d_in[8];
    const float* brs = (const float*)d_in[9];
    float* out = (float*)d_out;

    const size_t NE = (size_t)BATCH * C_DIM * HW;   // 4,194,304
    const size_t SL = 2 * NE;                       // 8 MiB slot
    char* ws = (char*)d_ws;
    _Float16* fccTh = (_Float16*)(ws + 0 * SL);
    _Float16* fccTl = (_Float16*)(ws + 1 * SL);
    _Float16* fssTh = (_Float16*)(ws + 2 * SL);
    _Float16* fssTl = (_Float16*)(ws + 3 * SL);
    _Float16* qTh   = (_Float16*)(ws + 4 * SL);
    _Float16* qTl   = (_Float16*)(ws + 5 * SL);
    _Float16* kTh   = (_Float16*)(ws + 0 * SL);   // overlay fccT (dead)
    _Float16* kTl   = (_Float16*)(ws + 1 * SL);
    _Float16* vhb   = (_Float16*)(ws + 6 * SL);
    _Float16* Op01  = (_Float16*)(ws + 2 * SL);   // overlay fssT (dead), 16 MiB
    _Float16* Op23  = (_Float16*)out;             // d_out scratch, 16 MiB
    float2*   mlb   = (float2*)  (ws + 7 * SL);   // 512 KiB
    _Float16* Wh4   = (_Float16*)(ws + 7 * SL + 524288);
    _Float16* Wl4   = (_Float16*)(ws + 7 * SL + 524288 + 524288);
    _Float16* frsTh = (_Float16*)(ws + 0 * SL);   // overlay kT (dead post-attn)
    _Float16* frsTl = (_Float16*)(ws + 1 * SL);

    dim3 tg(HW / 64, C_DIM / 64, BATCH);
    cvt_tsplit<<<tg, 256, 0, stream>>>(x_fcc, fccTh, fccTl);
    cvt_tsplit<<<tg, 256, 0, stream>>>(x_fss, fssTh, fssTl);
    wsplit<<<dim3(256, 4), 256, 0, stream>>>(w1, w2, w3, wrs, Wh4, Wl4);

    dim3 cg(BATCH * HW / 128, C_DIM / 64);
    conv_mfma<0><<<cg, 256, 0, stream>>>(Wh4,           Wl4,           fccTh, fccTl, b1,
                                         nullptr, nullptr, qTh, qTl);
    conv_mfma<0><<<cg, 256, 0, stream>>>(Wh4 + 65536,   Wl4 + 65536,   fssTh, fssTl, b2,
                                         nullptr, nullptr, kTh, kTl);
    conv_mfma<1><<<cg, 256, 0, stream>>>(Wh4 + 2*65536, Wl4 + 2*65536, fssTh, fssTl, b3,
                                         nullptr, nullptr, vhb, nullptr);

    attn_mfma<<<dim3(1024), 256, 0, stream>>>(qTh, qTl, kTh, kTl, vhb, Op01, Op23, mlb);
    merge4<<<dim3(2048), 256, 0, stream>>>(Op01, Op23, mlb, frsTh, frsTl);

    conv_mfma<2><<<cg, 256, 0, stream>>>(Wh4 + 3*65536, Wl4 + 3*65536, frsTh, frsTl, brs,
                                         x_fcc, out, nullptr, nullptr);
}

// Round 7
// 331.335 us; speedup vs baseline: 1.5755x; 1.5755x over previous
//
#include <hip/hip_runtime.h>
#include <math.h>
#include <stdint.h>

#define BATCH 4
#define C_DIM 256
#define HW    4096
#define KT    32
#define NSPLIT 2
#define KRANGE (HW / NSPLIT)      // 2048
#define NT_WG (KRANGE / KT)       // 64
#define LOG2E 1.44269504088896340736f

typedef _Float16 half8 __attribute__((ext_vector_type(8)));
typedef float f32x4 __attribute__((ext_vector_type(4)));
typedef int i32x4 __attribute__((ext_vector_type(4)));
typedef unsigned int u32;

#define MFMA16(a, b, c) __builtin_amdgcn_mfma_f32_16x16x32_f16(a, b, c, 0, 0, 0)

#define GLL16(gsrc, ldst) \
  __builtin_amdgcn_global_load_lds((const __attribute__((address_space(1))) u32*)(const void*)(gsrc), \
                                   (__attribute__((address_space(3))) u32*)(void*)(ldst), 16, 0, 0)

// ---------------------------------------------------------------------------
// cvt: x f32 [b][c][p] -> xT hi/lo fp16 [b][p][c]   (transpose + split)
// ---------------------------------------------------------------------------
__global__ __launch_bounds__(256) void cvt_tsplit(
    const float* __restrict__ x, _Float16* __restrict__ xh, _Float16* __restrict__ xl)
{
    __shared__ float Xs[64][65];
    const int b = blockIdx.z, c0 = blockIdx.y * 64, p0 = blockIdx.x * 64;
    const int tid = threadIdx.x;
    #pragma unroll
    for (int it = 0; it < 16; ++it) {
        int idx = tid + it * 256;
        int row = idx >> 6, col = idx & 63;
        Xs[row][col] = x[((size_t)b * C_DIM + c0 + row) * HW + p0 + col];
    }
    __syncthreads();
    #pragma unroll
    for (int it = 0; it < 16; ++it) {
        int idx = tid + it * 256;
        int p_l = idx >> 6, c_l = idx & 63;
        float v = Xs[c_l][p_l];
        _Float16 h = (_Float16)v;
        size_t g = ((size_t)b * HW + p0 + p_l) * C_DIM + c0 + c_l;
        xh[g] = h;
        xl[g] = (_Float16)(v - (float)h);
    }
}

// ---------------------------------------------------------------------------
// wsplit: 4 weight matrices f32 [256][256] -> Wh/Wl fp16 (natural layout)
// ---------------------------------------------------------------------------
__global__ __launch_bounds__(256) void wsplit(
    const float* __restrict__ w1, const float* __restrict__ w2,
    const float* __restrict__ w3, const float* __restrict__ w4,
    _Float16* __restrict__ Wh, _Float16* __restrict__ Wl)
{
    const int m = blockIdx.y;
    const float* src = (m == 0) ? w1 : (m == 1) ? w2 : (m == 2) ? w3 : w4;
    const int i = blockIdx.x * 256 + threadIdx.x;
    float v = src[i];
    _Float16 h = (_Float16)v;
    Wh[m * 65536 + i] = h;
    Wl[m * 65536 + i] = (_Float16)(v - (float)h);
}

// ---------------------------------------------------------------------------
// conv1x1 as split-fp16 MFMA GEMM (unchanged — proven).
// ---------------------------------------------------------------------------
template<int MODE>
__global__ __launch_bounds__(256, 3) void conv_mfma(
    const _Float16* __restrict__ Wh, const _Float16* __restrict__ Wl,
    const _Float16* __restrict__ Xh, const _Float16* __restrict__ Xl,
    const float* __restrict__ bias,
    const float* __restrict__ res, float* __restrict__ outf,
    _Float16* __restrict__ oh, _Float16* __restrict__ ol)
{
    __shared__ __align__(1024) char smem[49152];
    char* const AH = smem;
    char* const AL = smem + 8192;
    char* const BH = smem + 16384;
    char* const BL = smem + 32768;

    const int tid = threadIdx.x;
    const int lane = tid & 63;
    const int w = tid >> 6;
    const int l15 = lane & 15, l4 = lane >> 4;
    const int o0 = blockIdx.y * 64;
    const int gp0 = blockIdx.x * 128;

    auto stage = [&](int ks) {
        const int kc0 = ks * 64;
        #pragma unroll
        for (int i = 0; i < 2; ++i) {
            const int r0 = w * 16 + i * 8;
            const int row = r0 + (lane >> 3);
            const int cc = ((lane & 7) ^ (row & 7)) * 8 + kc0;
            const size_t g = (size_t)(o0 + row) * C_DIM + cc;
            GLL16(Wh + g, AH + r0 * 128);
            GLL16(Wl + g, AL + r0 * 128);
        }
        #pragma unroll
        for (int i = 0; i < 4; ++i) {
            const int r0 = w * 32 + i * 8;
            const int p = r0 + (lane >> 3);
            const int cc = ((lane & 7) ^ (p & 7)) * 8 + kc0;
            const size_t g = (size_t)(gp0 + p) * C_DIM + cc;
            GLL16(Xh + g, BH + r0 * 128);
            GLL16(Xl + g, BL + r0 * 128);
        }
    };

    f32x4 acc[4][4];
    #pragma unroll
    for (int i = 0; i < 4; ++i)
        #pragma unroll
        for (int j = 0; j < 4; ++j) {
            f32x4 z = {0.f, 0.f, 0.f, 0.f};
            acc[i][j] = z;
        }

    stage(0);
    for (int ks = 0; ks < 4; ++ks) {
        __syncthreads();
        #pragma unroll
        for (int s = 0; s < 2; ++s) {
            const int coff = s * 64 + l4 * 16;
            if (MODE == 0) {
                half8 ah[4], al[4], bh[2], bl[2];
                #pragma unroll
                for (int mt = 0; mt < 4; ++mt) {
                    const int ol_ = mt * 16 + l15;
                    const int sw = (ol_ & 7) << 4;
                    ah[mt] = *(const half8*)(AH + ol_ * 128 + (coff ^ sw));
                    al[mt] = *(const half8*)(AL + ol_ * 128 + (coff ^ sw));
                }
                #pragma unroll
                for (int nt = 0; nt < 2; ++nt) {
                    const int pl_ = w * 32 + nt * 16 + l15;
                    const int sw = (pl_ & 7) << 4;
                    bh[nt] = *(const half8*)(BH + pl_ * 128 + (coff ^ sw));
                    bl[nt] = *(const half8*)(BL + pl_ * 128 + (coff ^ sw));
                }
                #pragma unroll
                for (int mt = 0; mt < 4; ++mt)
                    #pragma unroll
                    for (int nt = 0; nt < 2; ++nt) {
                        acc[mt][nt] = MFMA16(ah[mt], bh[nt], acc[mt][nt]);
                        acc[mt][nt] = MFMA16(al[mt], bh[nt], acc[mt][nt]);
                        acc[mt][nt] = MFMA16(ah[mt], bl[nt], acc[mt][nt]);
                    }
            } else {
                half8 ah[2], al[2], bh[4], bl[4];
                #pragma unroll
                for (int mt = 0; mt < 2; ++mt) {
                    const int pl_ = w * 32 + mt * 16 + l15;
                    const int sw = (pl_ & 7) << 4;
                    ah[mt] = *(const half8*)(BH + pl_ * 128 + (coff ^ sw));
                    al[mt] = *(const half8*)(BL + pl_ * 128 + (coff ^ sw));
                }
                #pragma unroll
                for (int nt = 0; nt < 4; ++nt) {
                    const int ol_ = nt * 16 + l15;
                    const int sw = (ol_ & 7) << 4;
                    bh[nt] = *(const half8*)(AH + ol_ * 128 + (coff ^ sw));
                    bl[nt] = *(const half8*)(AL + ol_ * 128 + (coff ^ sw));
                }
                #pragma unroll
                for (int mt = 0; mt < 2; ++mt)
                    #pragma unroll
                    for (int nt = 0; nt < 4; ++nt) {
                        acc[mt][nt] = MFMA16(ah[mt], bh[nt], acc[mt][nt]);
                        acc[mt][nt] = MFMA16(al[mt], bh[nt], acc[mt][nt]);
                        acc[mt][nt] = MFMA16(ah[mt], bl[nt], acc[mt][nt]);
                    }
            }
        }
        __syncthreads();
        if (ks < 3) stage(ks + 1);
    }

    if (MODE == 0) {
        float bv[4][4];
        #pragma unroll
        for (int mt = 0; mt < 4; ++mt)
            #pragma unroll
            for (int r = 0; r < 4; ++r)
                bv[mt][r] = bias[o0 + mt * 16 + l4 * 4 + r];
        #pragma unroll
        for (int nt = 0; nt < 2; ++nt) {
            const size_t p = gp0 + w * 32 + nt * 16 + l15;
            #pragma unroll
            for (int mt = 0; mt < 4; ++mt) {
                _Float16 hb[4], lb[4];
                #pragma unroll
                for (int r = 0; r < 4; ++r) {
                    float v = acc[mt][nt][r] + bv[mt][r];
                    _Float16 h = (_Float16)v;
                    hb[r] = h;
                    lb[r] = (_Float16)(v - (float)h);
                }
                const size_t g = p * C_DIM + o0 + mt * 16 + l4 * 4;
                *(uint2*)(oh + g) = *(uint2*)hb;
                *(uint2*)(ol + g) = *(uint2*)lb;
            }
        }
    } else {
        float bv[4];
        #pragma unroll
        for (int nt = 0; nt < 4; ++nt) bv[nt] = bias[o0 + nt * 16 + l15];
        const int b = gp0 >> 12;
        #pragma unroll
        for (int mt = 0; mt < 2; ++mt) {
            const int sp = (gp0 & 4095) + w * 32 + mt * 16 + l4 * 4;
            #pragma unroll
            for (int nt = 0; nt < 4; ++nt) {
                const int o = o0 + nt * 16 + l15;
                const size_t base = ((size_t)b * C_DIM + o) * HW + sp;
                if (MODE == 1) {
                    _Float16 hb[4];
                    #pragma unroll
                    for (int r = 0; r < 4; ++r)
                        hb[r] = (_Float16)(acc[mt][nt][r] + bv[nt]);
                    *(uint2*)(oh + base) = *(uint2*)hb;
                } else {
                    f32x4 rv = *(const f32x4*)(res + base);
                    f32x4 vv;
                    #pragma unroll
                    for (int r = 0; r < 4; ++r) vv[r] = acc[mt][nt][r] + bv[nt] + rv[r];
                    *(f32x4*)(outf + base) = vv;
                }
            }
        }
    }
}

// ---------------------------------------------------------------------------
// MFMA flash attention v4: R6's swapped-QK^T + in-register softmax math
// (proven) on the R4 2-barrier latency-hiding schedule (proven):
//   B1 -> QK^T -> B2 -> stage K(t+1), V(t+1,alt) -> softmax(reg) -> PV(cur)
// K single-buffered (all K reads complete before B2), V double-buffered.
// LDS 64KB -> 2 blocks/CU. k-split x2, XCD-affine (b,ks) = blockIdx&7.
// ---------------------------------------------------------------------------
__global__ __launch_bounds__(256, 2) void attn_mfma(
    const _Float16* __restrict__ qTh, const _Float16* __restrict__ qTl,
    const _Float16* __restrict__ kTh, const _Float16* __restrict__ kTl,
    const _Float16* __restrict__ vh,
    _Float16* __restrict__ Op0, _Float16* __restrict__ Op1,
    float2* __restrict__ ml)
{
    __shared__ __align__(1024) char smem[65536];
    char* const KH = smem;              // [32 ki][256 c] fp16, 512B rows, swz
    char* const KL = smem + 16384;
    char* const V0 = smem + 32768;      // [256 c][32 k] fp16, 64B rows, swz
    char* const V1 = smem + 49152;

    const int raw = blockIdx.x;         // 512 WGs; (raw&7) -> XCD-affine (b,ks)
    const int combo = raw & 7;
    const int b  = combo >> 1;
    const int ks = combo & 1;
    const int q0 = (raw >> 3) * 64;
    const int kbase = ks * KRANGE;

    const int tid = threadIdx.x;
    const int lane = tid & 63;
    const int w = tid >> 6;
    const int l15 = lane & 15, l4 = lane >> 4;
    const size_t cb = (size_t)b * C_DIM * HW;

    // Q fragments (B-frag: col=q=l15, c-chunk=(lane>>4)*8+i per 32-c step)
    half8 qh[8], ql[8];
    {
        const size_t base = ((size_t)b * HW + (q0 + w * 16 + l15)) * C_DIM + l4 * 8;
        #pragma unroll
        for (int s = 0; s < 8; ++s) {
            qh[s] = *(const half8*)(qTh + base + s * 32);
            ql[s] = *(const half8*)(qTl + base + s * 32);
        }
    }

    auto stageK = [&](int t) {
        const int k0 = kbase + t * KT;
        #pragma unroll
        for (int i = 0; i < 4; ++i) {
            const int r0 = w * 8 + i * 2;
            const int row = r0 + (lane >> 5);
            const int cc = ((lane & 31) ^ (row & 7)) * 8;
            const size_t gs = ((size_t)b * HW + k0 + row) * C_DIM + cc;
            GLL16(kTh + gs, KH + r0 * 512);
            GLL16(kTl + gs, KL + r0 * 512);
        }
    };
    auto stageV = [&](int t, char* VB) {
        const int k0 = kbase + t * KT;
        #pragma unroll
        for (int i = 0; i < 4; ++i) {
            const int c0w = w * 64 + i * 16;
            const int c = c0w + (lane >> 2);
            const int kk = ((lane & 3) ^ ((c >> 1) & 3)) * 8;
            const size_t gs = (cb + (size_t)c * HW) + k0 + kk;
            GLL16(vh + gs, VB + c0w * 64);
        }
    };

    stageK(0);
    stageV(0, V0);

    f32x4 accv[16];                     // O[c = mt*16 + l4*4 + r][q = l15]
    #pragma unroll
    for (int mt = 0; mt < 16; ++mt) {
        f32x4 z = {0.f, 0.f, 0.f, 0.f};
        accv[mt] = z;
    }
    float m_run = -INFINITY, l_run = 0.f;

    for (int t = 0; t < NT_WG; ++t) {
        __syncthreads();   // B1: K(t)/V(t) staged (drains vmcnt)

        // ---- QK^T swapped: sacc[nt] = S^T[k = nt*16 + l4*4 + r][q = l15]
        f32x4 sacc[2];
        #pragma unroll
        for (int nt = 0; nt < 2; ++nt) {
            f32x4 z = {0.f, 0.f, 0.f, 0.f};
            sacc[nt] = z;
        }
        #pragma unroll
        for (int s = 0; s < 8; ++s) {
            const int coff = s * 64 + l4 * 16;
            #pragma unroll
            for (int nt = 0; nt < 2; ++nt) {
                const int ki = nt * 16 + l15;      // A-frag row = k
                const int sw = (ki & 7) << 4;
                half8 kf = *(const half8*)(KH + ki * 512 + (coff ^ sw));
                half8 lf = *(const half8*)(KL + ki * 512 + (coff ^ sw));
                sacc[nt] = MFMA16(kf, qh[s], sacc[nt]);
                sacc[nt] = MFMA16(kf, ql[s], sacc[nt]);
                sacc[nt] = MFMA16(lf, qh[s], sacc[nt]);
            }
        }
        __syncthreads();   // B2: all K reads done

        // ---- prefetch next tile NOW; latency hidden under softmax + PV
        if (t + 1 < NT_WG) {
            stageK(t + 1);
            stageV(t + 1, ((t + 1) & 1) ? V1 : V0);
        }

        // ---- in-register online softmax for q-column l15
        float mx = fmaxf(fmaxf(fmaxf(sacc[0][0], sacc[0][1]), fmaxf(sacc[0][2], sacc[0][3])),
                         fmaxf(fmaxf(sacc[1][0], sacc[1][1]), fmaxf(sacc[1][2], sacc[1][3])));
        mx = fmaxf(mx, __shfl_xor(mx, 16));
        mx = fmaxf(mx, __shfl_xor(mx, 32));
        const float mnew = fmaxf(m_run, mx);
        const float sc = exp2f((m_run - mnew) * LOG2E);
        float p[2][4];
        float rs = 0.f;
        #pragma unroll
        for (int nt = 0; nt < 2; ++nt)
            #pragma unroll
            for (int r = 0; r < 4; ++r) {
                p[nt][r] = exp2f((sacc[nt][r] - mnew) * LOG2E);
                rs += p[nt][r];
            }
        rs += __shfl_xor(rs, 16);
        rs += __shfl_xor(rs, 32);
        l_run = l_run * sc + rs;
        m_run = mnew;

        // ---- build PV B-frag: element i of half8 = P[k=l4*8+i][q=l15]
        int d0a = __builtin_bit_cast(int, __builtin_amdgcn_cvt_pkrtz(p[0][0], p[0][1]));
        int d0b = __builtin_bit_cast(int, __builtin_amdgcn_cvt_pkrtz(p[0][2], p[0][3]));
        int d1a = __builtin_bit_cast(int, __builtin_amdgcn_cvt_pkrtz(p[1][0], p[1][1]));
        int d1b = __builtin_bit_cast(int, __builtin_amdgcn_cvt_pkrtz(p[1][2], p[1][3]));
        const int src0 = l15 + (((l4 & 1) << 1) << 4);   // lane l15+16*(2*(l4&1))
        const int src1 = src0 + 16;
        const int a0 = __shfl(d0a, src0), a1 = __shfl(d0b, src0);
        const int a2 = __shfl(d0a, src1), a3 = __shfl(d0b, src1);
        const int b0 = __shfl(d1a, src0), b1 = __shfl(d1b, src0);
        const int b2 = __shfl(d1a, src1), b3 = __shfl(d1b, src1);
        const bool hi = (l4 >= 2);       // target k>=16 -> source nt=1
        i32x4 pw;
        pw[0] = hi ? b0 : a0;
        pw[1] = hi ? b1 : a1;
        pw[2] = hi ? b2 : a2;
        pw[3] = hi ? b3 : a3;
        const half8 pfrag = __builtin_bit_cast(half8, pw);

        // ---- rescale O, then O += V·P  (reads CURRENT V buffer)
        const char* VB = (t & 1) ? V1 : V0;
        #pragma unroll
        for (int mt = 0; mt < 16; ++mt) {
            accv[mt][0] *= sc; accv[mt][1] *= sc;
            accv[mt][2] *= sc; accv[mt][3] *= sc;
        }
        #pragma unroll
        for (int mt = 0; mt < 16; ++mt) {
            const int c = mt * 16 + l15;     // A-frag row = c
            const half8 vf = *(const half8*)(VB + c * 64 + ((l4 ^ ((c >> 1) & 3)) << 4));
            accv[mt] = MFMA16(vf, pfrag, accv[mt]);
        }
    }

    // ---- epilogue: normalized fp16 partial + (m,l)
    const float inv = 1.0f / l_run;
    _Float16* Op = ks ? Op1 : Op0;
    const int q = q0 + w * 16 + l15;
    const size_t gq = ((size_t)b * HW + q) * C_DIM;
    #pragma unroll
    for (int mt = 0; mt < 16; ++mt) {
        _Float16 hb[4];
        #pragma unroll
        for (int r = 0; r < 4; ++r) hb[r] = (_Float16)(accv[mt][r] * inv);
        *(uint2*)(Op + gq + mt * 16 + l4 * 4) = *(uint2*)hb;
    }
    if (l4 == 0) ml[((size_t)ks * BATCH + b) * HW + q] = make_float2(m_run, l_run);
}

// ---------------------------------------------------------------------------
// merge2: combine the two k-split partials -> frsT hi/lo fp16 [b][q][c]
// ---------------------------------------------------------------------------
__global__ __launch_bounds__(256) void merge2(
    const _Float16* __restrict__ Op0, const _Float16* __restrict__ Op1,
    const float2* __restrict__ ml,
    _Float16* __restrict__ fh, _Float16* __restrict__ fl)
{
    const int gi = blockIdx.x * 256 + threadIdx.x;   // 0..524287
    const int c8 = gi & 31;
    const int q  = (gi >> 5) & 4095;
    const int b  = gi >> 17;
    const size_t iq = (size_t)b * HW + q;

    const float2 e0 = ml[iq];
    const float2 e1 = ml[(size_t)BATCH * HW + iq];
    const float M = fmaxf(e0.x, e1.x);
    float w0 = e0.y * exp2f((e0.x - M) * LOG2E);
    float w1 = e1.y * exp2f((e1.x - M) * LOG2E);
    const float r = 1.0f / (w0 + w1);
    w0 *= r; w1 *= r;

    const size_t gb = iq * C_DIM + c8 * 8;
    half8 p0 = *(const half8*)(Op0 + gb);
    half8 p1 = *(const half8*)(Op1 + gb);
    _Float16 hb[8], lb[8];
    #pragma unroll
    for (int i = 0; i < 8; ++i) {
        float v = w0 * (float)p0[i] + w1 * (float)p1[i];
        _Float16 h = (_Float16)v;
        hb[i] = h;
        lb[i] = (_Float16)(v - (float)h);
    }
    *(half8*)(fh + gb) = *(half8*)hb;
    *(half8*)(fl + gb) = *(half8*)lb;
}

// ---------------------------------------------------------------------------
// Workspace (8 slots x 8 MiB = 64 MiB, R1-proven size). Overlays:
//   s0,s1: fccT -> kT -> frsT | s2: fssTh -> Op0 | s3: fssTl
//   s4,s5: qT | s6: vhb | s7: ml(256K)+Wh(512K)+Wl(512K)
//   Op1 -> d_out scratch (consumed by merge2 before final conv rewrites).
// ---------------------------------------------------------------------------
extern "C" void kernel_launch(void* const* d_in, const int* in_sizes, int n_in,
                              void* d_out, int out_size, void* d_ws, size_t ws_size,
                              hipStream_t stream)
{
    const float* x_fcc = (const float*)d_in[0];
    const float* x_fss = (const float*)d_in[1];
    const float* w1  = (const float*)d_in[2];
    const float* b1  = (const float*)d_in[3];
    const float* w2  = (const float*)d_in[4];
    const float* b2  = (const float*)d_in[5];
    const float* w3  = (const float*)d_in[6];
    const float* b3  = (const float*)d_in[7];
    const float* wrs = (const float*)d_in[8];
    const float* brs = (const float*)d_in[9];
    float* out = (float*)d_out;

    const size_t NE = (size_t)BATCH * C_DIM * HW;   // 4,194,304
    const size_t SL = 2 * NE;                       // 8 MiB slot
    char* ws = (char*)d_ws;
    _Float16* fccTh = (_Float16*)(ws + 0 * SL);
    _Float16* fccTl = (_Float16*)(ws + 1 * SL);
    _Float16* fssTh = (_Float16*)(ws + 2 * SL);
    _Float16* fssTl = (_Float16*)(ws + 3 * SL);
    _Float16* qTh   = (_Float16*)(ws + 4 * SL);
    _Float16* qTl   = (_Float16*)(ws + 5 * SL);
    _Float16* kTh   = (_Float16*)(ws + 0 * SL);   // overlay fccT (dead)
    _Float16* kTl   = (_Float16*)(ws + 1 * SL);
    _Float16* vhb   = (_Float16*)(ws + 6 * SL);
    _Float16* Op0   = (_Float16*)(ws + 2 * SL);   // overlay fssTh (dead), 8 MiB
    _Float16* Op1   = (_Float16*)out;             // d_out scratch, 8 MiB of 16
    float2*   mlb   = (float2*)  (ws + 7 * SL);   // 256 KiB
    _Float16* Wh4   = (_Float16*)(ws + 7 * SL + 262144);
    _Float16* Wl4   = (_Float16*)(ws + 7 * SL + 262144 + 524288);
    _Float16* frsTh = (_Float16*)(ws + 0 * SL);   // overlay kT (dead post-attn)
    _Float16* frsTl = (_Float16*)(ws + 1 * SL);

    dim3 tg(HW / 64, C_DIM / 64, BATCH);
    cvt_tsplit<<<tg, 256, 0, stream>>>(x_fcc, fccTh, fccTl);
    cvt_tsplit<<<tg, 256, 0, stream>>>(x_fss, fssTh, fssTl);
    wsplit<<<dim3(256, 4), 256, 0, stream>>>(w1, w2, w3, wrs, Wh4, Wl4);

    dim3 cg(BATCH * HW / 128, C_DIM / 64);
    conv_mfma<0><<<cg, 256, 0, stream>>>(Wh4,           Wl4,           fccTh, fccTl, b1,
                                         nullptr, nullptr, qTh, qTl);
    conv_mfma<0><<<cg, 256, 0, stream>>>(Wh4 + 65536,   Wl4 + 65536,   fssTh, fssTl, b2,
                                         nullptr, nullptr, kTh, kTl);
    conv_mfma<1><<<cg, 256, 0, stream>>>(Wh4 + 2*65536, Wl4 + 2*65536, fssTh, fssTl, b3,
                                         nullptr, nullptr, vhb, nullptr);

    attn_mfma<<<dim3(512), 256, 0, stream>>>(qTh, qTl, kTh, kTl, vhb, Op0, Op1, mlb);
    merge2<<<dim3(2048), 256, 0, stream>>>(Op0, Op1, mlb, frsTh, frsTl);

    conv_mfma<2><<<cg, 256, 0, stream>>>(Wh4 + 3*65536, Wl4 + 3*65536, frsTh, frsTl, brs,
                                         x_fcc, out, nullptr, nullptr);
}